// Round 1
// baseline (70.987 us; speedup 1.0000x reference)
//
#include <hip/hip_runtime.h>
#include <hip/hip_bf16.h>

typedef float f4 __attribute__((ext_vector_type(4)));
typedef unsigned short u16x8 __attribute__((ext_vector_type(8)));

#define QSCALE 0.17677669529663689f  // 32^-0.5

__device__ inline float b2f(unsigned short u){
  union{unsigned int i; float f;} z; z.i = ((unsigned int)u)<<16; return z.f;
}
__device__ inline unsigned short f2b(float f){
  union{float f; unsigned int i;} z; z.f=f;
  unsigned int i = z.i;
  return (unsigned short)((i + 0x7FFFu + ((i>>16)&1u)) >> 16);
}

// ---------------- Kernel 1: qkv = x @ w_qkv + b_qkv  (fp32 in, bf16 out) ----
// grid (256, 6), block 256.  out columns: [0,128)=q (scaled), [128,256)=k, [256,384)=v
__global__ __launch_bounds__(256) void k_qkv(const float* __restrict__ x,
    const float* __restrict__ w, const float* __restrict__ bias,
    unsigned short* __restrict__ qo, unsigned short* __restrict__ ko,
    unsigned short* __restrict__ vo)
{
  __shared__ float Xs[64][132];
  __shared__ float Bs[128][68];
  const int t = threadIdx.x;
  const int m0 = blockIdx.x * 64;
  const int n0 = blockIdx.y * 64;
  for (int i = t; i < 2048; i += 256){
    int m = i >> 5, kc = (i & 31) << 2;
    *(f4*)&Xs[m][kc] = *(const f4*)&x[(m0+m)*128 + kc];
  }
  for (int i = t; i < 2048; i += 256){
    int r = i >> 4, nc = (i & 15) << 2;
    *(f4*)&Bs[r][nc] = *(const f4*)&w[r*384 + n0 + nc];
  }
  __syncthreads();
  const int tx = t & 15, ty = t >> 4;
  float acc[4][4] = {};
  for (int k = 0; k < 128; k += 4){
    f4 a4[4], b4[4];
#pragma unroll
    for (int i=0;i<4;++i) a4[i] = *(const f4*)&Xs[ty*4+i][k];
#pragma unroll
    for (int kk=0;kk<4;++kk) b4[kk] = *(const f4*)&Bs[k+kk][tx*4];
#pragma unroll
    for (int i=0;i<4;++i)
#pragma unroll
      for (int kk=0;kk<4;++kk)
#pragma unroll
        for (int j=0;j<4;++j)
          acc[i][j] += a4[i][kk] * b4[kk][j];
  }
#pragma unroll
  for (int i=0;i<4;++i){
    int row = m0 + ty*4 + i;
#pragma unroll
    for (int j=0;j<4;j+=2){
      int c = n0 + tx*4 + j;
      float v0 = acc[i][j]   + bias[c];
      float v1 = acc[i][j+1] + bias[c+1];
      int which = c >> 7, rem = c & 127;
      if (which == 0){ v0 *= QSCALE; v1 *= QSCALE; }
      unsigned short* dst = which==0 ? qo : (which==1 ? ko : vo);
      *(unsigned int*)&dst[row*128 + rem] =
          (unsigned int)f2b(v0) | ((unsigned int)f2b(v1) << 16);
    }
  }
}

// ---------------- Kernel 2: neighborhood attention ----------------
// grid (8, 8, 4) = (tile_j, tile_i, batch), block 256.
// thread t -> local token lt = t>>2 (8x8 tile), head h = t&3.
// LDS: 14x14 halo of k and v (bf16, stride 136), rpb (fp32).
__global__ __launch_bounds__(256) void k_attn(
    const unsigned short* __restrict__ qg,
    const unsigned short* __restrict__ kg,
    const unsigned short* __restrict__ vg,
    const float* __restrict__ rpb,
    unsigned short* __restrict__ ao)
{
  __shared__ unsigned short ks[196*136];
  __shared__ unsigned short vs[196*136];
  __shared__ float rs[676];
  const int t = threadIdx.x;
  const int b = blockIdx.z;
  const int th0 = blockIdx.y * 8, tw0 = blockIdx.x * 8;
  const int bi0 = min(max(th0-3,0),50);
  const int bj0 = min(max(tw0-3,0),50);
  for (int c = t; c < 3136; c += 256){
    int tok = c >> 4, part = c & 15;
    int trow = tok/14;
    int gi = bi0 + trow;
    int gj = bj0 + (tok - trow*14);
    int go = ((b*64+gi)*64+gj)*128 + part*8;
    int lo = tok*136 + part*8;
    *(u16x8*)&ks[lo] = *(const u16x8*)&kg[go];
    *(u16x8*)&vs[lo] = *(const u16x8*)&vg[go];
  }
  for (int c = t; c < 676; c += 256) rs[c] = rpb[c];
  __syncthreads();

  const int lt = t >> 2, h = t & 3;
  const int ti = th0 + (lt >> 3), tj = tw0 + (lt & 7);
  const int si = min(max(ti-3,0),57), sj = min(max(tj-3,0),57);
  const int li = si - bi0, lj = sj - bj0;       // LDS halo offsets
  const int ri = si - ti + 6, rj = sj - tj + 6; // rpb offsets (0..6)

  float q[32];
  {
    int qb = ((b*64+ti)*64+tj)*128 + h*32;
#pragma unroll
    for (int j=0;j<4;++j){
      u16x8 u = *(const u16x8*)&qg[qb + j*8];
#pragma unroll
      for (int e=0;e<8;++e) q[j*8+e] = b2f(u[e]);
    }
  }
  float m = -1e30f, l = 0.f, o[32];
#pragma unroll
  for (int d=0; d<32; ++d) o[d] = 0.f;

  for (int pi=0; pi<7; ++pi){
    const int rowoff = (li+pi)*14;
    const float* rrow = &rs[h*169 + (ri+pi)*13 + rj];
    for (int pj=0; pj<7; ++pj){
      int lo = (rowoff + lj + pj)*136 + h*32;
      float s = rrow[pj];
#pragma unroll
      for (int j=0;j<4;++j){
        u16x8 kk = *(const u16x8*)&ks[lo + j*8];
#pragma unroll
        for (int e=0;e<8;++e) s += q[j*8+e]*b2f(kk[e]);
      }
      float mn = fmaxf(m, s);
      float sc = __expf(m - mn);
      float e  = __expf(s - mn);
      l = l*sc + e;
#pragma unroll
      for (int j=0;j<4;++j){
        u16x8 vv = *(const u16x8*)&vs[lo + j*8];
#pragma unroll
        for (int e2=0;e2<8;++e2){
          int d = j*8+e2;
          o[d] = o[d]*sc + e*b2f(vv[e2]);
        }
      }
      m = mn;
    }
  }
  float inv = 1.f / l;
  int ob = ((b*64+ti)*64+tj)*128 + h*32;
#pragma unroll
  for (int j=0;j<16;++j){
    *(unsigned int*)&ao[ob + 2*j] =
      (unsigned int)f2b(o[2*j]*inv) | ((unsigned int)f2b(o[2*j+1]*inv)<<16);
  }
}

// ---------------- Kernel 3: out = ao @ w_proj + b_proj (bf16 A, fp32 out) ---
// grid (256, 2), block 256.
__global__ __launch_bounds__(256) void k_proj(
    const unsigned short* __restrict__ a,
    const float* __restrict__ w, const float* __restrict__ bias,
    float* __restrict__ out)
{
  __shared__ float Xs[64][132];
  __shared__ float Bs[128][68];
  const int t = threadIdx.x;
  const int m0 = blockIdx.x * 64;
  const int n0 = blockIdx.y * 64;
  for (int i = t; i < 1024; i += 256){
    int m = i >> 4, kc = (i & 15) << 3;
    u16x8 u = *(const u16x8*)&a[(m0+m)*128 + kc];
    f4 lo4 = { b2f(u[0]), b2f(u[1]), b2f(u[2]), b2f(u[3]) };
    f4 hi4 = { b2f(u[4]), b2f(u[5]), b2f(u[6]), b2f(u[7]) };
    *(f4*)&Xs[m][kc] = lo4;
    *(f4*)&Xs[m][kc+4] = hi4;
  }
  for (int i = t; i < 2048; i += 256){
    int r = i >> 4, nc = (i & 15) << 2;
    *(f4*)&Bs[r][nc] = *(const f4*)&w[r*128 + n0 + nc];
  }
  __syncthreads();
  const int tx = t & 15, ty = t >> 4;
  float acc[4][4] = {};
  for (int k = 0; k < 128; k += 4){
    f4 a4[4], b4[4];
#pragma unroll
    for (int i=0;i<4;++i) a4[i] = *(const f4*)&Xs[ty*4+i][k];
#pragma unroll
    for (int kk=0;kk<4;++kk) b4[kk] = *(const f4*)&Bs[k+kk][tx*4];
#pragma unroll
    for (int i=0;i<4;++i)
#pragma unroll
      for (int kk=0;kk<4;++kk)
#pragma unroll
        for (int j=0;j<4;++j)
          acc[i][j] += a4[i][kk]*b4[kk][j];
  }
#pragma unroll
  for (int i=0;i<4;++i){
    int row = m0 + ty*4 + i;
    f4 r4;
#pragma unroll
    for (int j=0;j<4;++j) r4[j] = acc[i][j] + bias[n0 + tx*4 + j];
    *(f4*)&out[row*128 + n0 + tx*4] = r4;
  }
}

extern "C" void kernel_launch(void* const* d_in, const int* in_sizes, int n_in,
                              void* d_out, int out_size, void* d_ws, size_t ws_size,
                              hipStream_t stream) {
  const float* x      = (const float*)d_in[0];
  const float* w_qkv  = (const float*)d_in[1];
  const float* b_qkv  = (const float*)d_in[2];
  const float* rpb    = (const float*)d_in[3];
  const float* w_proj = (const float*)d_in[4];
  const float* b_proj = (const float*)d_in[5];
  float* out = (float*)d_out;

  unsigned short* qo = (unsigned short*)d_ws;
  unsigned short* ko = qo + 16384*128;
  unsigned short* vo = ko + 16384*128;
  unsigned short* ao = vo + 16384*128;

  k_qkv<<<dim3(256, 6), 256, 0, stream>>>(x, w_qkv, b_qkv, qo, ko, vo);
  k_attn<<<dim3(8, 8, 4), 256, 0, stream>>>(qo, ko, vo, rpb, ao);
  k_proj<<<dim3(256, 2), 256, 0, stream>>>(ao, w_proj, b_proj, out);
}

// Round 2
// 53.160 us; speedup vs baseline: 1.3354x; 1.3354x over previous
//
#include <hip/hip_runtime.h>
#include <hip/hip_bf16.h>

typedef float f4 __attribute__((ext_vector_type(4)));
typedef float f32x4 __attribute__((ext_vector_type(4)));
typedef unsigned short u16x8 __attribute__((ext_vector_type(8)));
typedef short short8 __attribute__((ext_vector_type(8)));

#define QSCALE 0.17677669529663689f  // 32^-0.5

__device__ inline float b2f(unsigned short u){
  union{unsigned int i; float f;} z; z.i = ((unsigned int)u)<<16; return z.f;
}
__device__ inline unsigned short f2b(float f){
  union{float f; unsigned int i;} z; z.f=f;
  unsigned int i = z.i;
  return (unsigned short)((i + 0x7FFFu + ((i>>16)&1u)) >> 16);
}

// ---------------- Kernel 0: transpose+convert weights ----------------
// wT[n][k] = bf16(w_qkv[k][n])  (384x128), wpT[n][k] = bf16(w_proj[k][n]) (128x128)
// grid 16 blocks x 256 threads; blocks 0..11 -> qkv, 12..15 -> proj.
__global__ __launch_bounds__(256) void k_prep(const float* __restrict__ wq,
    const float* __restrict__ wp, unsigned short* __restrict__ wT,
    unsigned short* __restrict__ wpT)
{
  __shared__ float T[32][129];
  const int b = blockIdx.x, t = threadIdx.x;
  const float* src; unsigned short* dst; int N, n0;
  if (b < 12){ src = wq; dst = wT;  N = 384; n0 = b*32; }
  else       { src = wp; dst = wpT; N = 128; n0 = (b-12)*32; }
  for (int i = t; i < 4096; i += 256){
    int k = i >> 5, c = i & 31;
    T[c][k] = src[k*N + n0 + c];
  }
  __syncthreads();
  const int n = t >> 3, k0 = (t & 7) << 4;
#pragma unroll
  for (int e = 0; e < 2; ++e){
    u16x8 o;
#pragma unroll
    for (int j = 0; j < 8; ++j) o[j] = f2b(T[n][k0 + e*8 + j]);
    *(u16x8*)&dst[(n0+n)*128 + k0 + e*8] = o;
  }
}

// ---------------- Kernel 1: qkv = x @ w_qkv + b_qkv (MFMA bf16) ----------------
// grid (256, 3): m0 = bx*64, plane = by (0=q scaled,1=k,2=v). block 256 (4 waves).
// Block tile 64(M) x 128(N), K=128 fully staged. Wave tile 32x64.
__global__ __launch_bounds__(256) void k_qkv_mfma(const float* __restrict__ x,
    const unsigned short* __restrict__ wT, const float* __restrict__ bias,
    unsigned short* __restrict__ qo, unsigned short* __restrict__ ko,
    unsigned short* __restrict__ vo)
{
  __shared__ short lds[64*128 + 128*128];   // As | Bs, 48KB
  short* As = lds;             // [64][128] bf16, row stride 256B, XOR-swizzled
  short* Bs = lds + 64*128;    // [128][128] bf16 (col-major: [n][k]), swizzled
  const int t = threadIdx.x;
  const int m0 = blockIdx.x * 64;
  const int ny = blockIdx.y;
  const int n0 = ny * 128;

  // stage A: x fp32 -> bf16, swizzled
  for (int c = t; c < 1024; c += 256){
    int row = c >> 4, k0 = (c & 15) << 3;
    const float* p = &x[(m0+row)*128 + k0];
    f4 lo = *(const f4*)p, hi = *(const f4*)(p+4);
    u16x8 v;
    v[0]=f2b(lo[0]); v[1]=f2b(lo[1]); v[2]=f2b(lo[2]); v[3]=f2b(lo[3]);
    v[4]=f2b(hi[0]); v[5]=f2b(hi[1]); v[6]=f2b(hi[2]); v[7]=f2b(hi[3]);
    int byte = (row<<8) + (k0<<1);
    *(u16x8*)((char*)As + (byte ^ ((row&7)<<4))) = v;
  }
  // stage B: wT rows n0..n0+127
  for (int c = t; c < 2048; c += 256){
    int n = c >> 4, k0 = (c & 15) << 3;
    u16x8 v = *(const u16x8*)&wT[(n0+n)*128 + k0];
    int byte = (n<<8) + (k0<<1);
    *(u16x8*)((char*)Bs + (byte ^ ((n&7)<<4))) = v;
  }
  __syncthreads();

  const int w = t >> 6, l = t & 63;
  const int wm = (w >> 1) * 32, wn = (w & 1) * 64;
  const int lr = l & 15, lk = (l >> 4) << 3;
  f32x4 acc[2][4] = {};
#pragma unroll
  for (int k0 = 0; k0 < 128; k0 += 32){
    const int koff = k0 + lk;
    short8 a[2], bf[4];
#pragma unroll
    for (int fm = 0; fm < 2; ++fm){
      int row = wm + fm*16 + lr;
      int byte = (row<<8) + (koff<<1);
      a[fm] = *(short8*)((char*)As + (byte ^ ((row&7)<<4)));
    }
#pragma unroll
    for (int fn = 0; fn < 4; ++fn){
      int rn = wn + fn*16 + lr;
      int byte = (rn<<8) + (koff<<1);
      bf[fn] = *(short8*)((char*)Bs + (byte ^ ((rn&7)<<4)));
    }
#pragma unroll
    for (int fm = 0; fm < 2; ++fm)
#pragma unroll
      for (int fn = 0; fn < 4; ++fn)
        acc[fm][fn] = __builtin_amdgcn_mfma_f32_16x16x32_bf16(a[fm], bf[fn], acc[fm][fn], 0, 0, 0);
  }
  __syncthreads();

  // epilogue: frag layout col=lane&15, row=(lane>>4)*4+reg -> LDS -> coalesced store
  unsigned short* C = (unsigned short*)lds;   // [64][136]
  const float scale = (ny == 0) ? QSCALE : 1.0f;
#pragma unroll
  for (int fm = 0; fm < 2; ++fm)
#pragma unroll
    for (int fn = 0; fn < 4; ++fn){
      int col = wn + fn*16 + lr;
      float bv = bias[n0 + col];
#pragma unroll
      for (int r = 0; r < 4; ++r){
        int row = wm + fm*16 + ((l>>4)<<2) + r;
        C[row*136 + col] = f2b((acc[fm][fn][r] + bv) * scale);
      }
    }
  __syncthreads();
  unsigned short* dst = ny==0 ? qo : (ny==1 ? ko : vo);
  for (int c = t; c < 1024; c += 256){
    int row = c >> 4, k0 = (c & 15) << 3;
    *(u16x8*)&dst[(m0+row)*128 + k0] = *(u16x8*)&C[row*136 + k0];
  }
}

// ---------------- Kernel 2: neighborhood attention (unchanged) ----------------
__global__ __launch_bounds__(256) void k_attn(
    const unsigned short* __restrict__ qg,
    const unsigned short* __restrict__ kg,
    const unsigned short* __restrict__ vg,
    const float* __restrict__ rpb,
    unsigned short* __restrict__ ao)
{
  __shared__ unsigned short ks[196*136];
  __shared__ unsigned short vs[196*136];
  __shared__ float rs[676];
  const int t = threadIdx.x;
  const int b = blockIdx.z;
  const int th0 = blockIdx.y * 8, tw0 = blockIdx.x * 8;
  const int bi0 = min(max(th0-3,0),50);
  const int bj0 = min(max(tw0-3,0),50);
  for (int c = t; c < 3136; c += 256){
    int tok = c >> 4, part = c & 15;
    int trow = tok/14;
    int gi = bi0 + trow;
    int gj = bj0 + (tok - trow*14);
    int go = ((b*64+gi)*64+gj)*128 + part*8;
    int lo = tok*136 + part*8;
    *(u16x8*)&ks[lo] = *(const u16x8*)&kg[go];
    *(u16x8*)&vs[lo] = *(const u16x8*)&vg[go];
  }
  for (int c = t; c < 676; c += 256) rs[c] = rpb[c];
  __syncthreads();

  const int lt = t >> 2, h = t & 3;
  const int ti = th0 + (lt >> 3), tj = tw0 + (lt & 7);
  const int si = min(max(ti-3,0),57), sj = min(max(tj-3,0),57);
  const int li = si - bi0, lj = sj - bj0;
  const int ri = si - ti + 6, rj = sj - tj + 6;

  float q[32];
  {
    int qb = ((b*64+ti)*64+tj)*128 + h*32;
#pragma unroll
    for (int j=0;j<4;++j){
      u16x8 u = *(const u16x8*)&qg[qb + j*8];
#pragma unroll
      for (int e=0;e<8;++e) q[j*8+e] = b2f(u[e]);
    }
  }
  float m = -1e30f, l = 0.f, o[32];
#pragma unroll
  for (int d=0; d<32; ++d) o[d] = 0.f;

  for (int pi=0; pi<7; ++pi){
    const int rowoff = (li+pi)*14;
    const float* rrow = &rs[h*169 + (ri+pi)*13 + rj];
    for (int pj=0; pj<7; ++pj){
      int lo = (rowoff + lj + pj)*136 + h*32;
      float s = rrow[pj];
#pragma unroll
      for (int j=0;j<4;++j){
        u16x8 kk = *(const u16x8*)&ks[lo + j*8];
#pragma unroll
        for (int e=0;e<8;++e) s += q[j*8+e]*b2f(kk[e]);
      }
      float mn = fmaxf(m, s);
      float sc = __expf(m - mn);
      float e  = __expf(s - mn);
      l = l*sc + e;
#pragma unroll
      for (int j=0;j<4;++j){
        u16x8 vv = *(const u16x8*)&vs[lo + j*8];
#pragma unroll
        for (int e2=0;e2<8;++e2){
          int d = j*8+e2;
          o[d] = o[d]*sc + e*b2f(vv[e2]);
        }
      }
      m = mn;
    }
  }
  float inv = 1.f / l;
  int ob = ((b*64+ti)*64+tj)*128 + h*32;
#pragma unroll
  for (int j=0;j<16;++j){
    *(unsigned int*)&ao[ob + 2*j] =
      (unsigned int)f2b(o[2*j]*inv) | ((unsigned int)f2b(o[2*j+1]*inv)<<16);
  }
}

// ---------------- Kernel 3: out = ao @ w_proj + b_proj (MFMA bf16, fp32 out) ---
// grid (256): m0 = bx*64. Block tile 64x128, K=128.
__global__ __launch_bounds__(256) void k_proj_mfma(
    const unsigned short* __restrict__ a,
    const unsigned short* __restrict__ wpT, const float* __restrict__ bias,
    float* __restrict__ out)
{
  __shared__ short lds[64*128 + 128*128];   // 48KB
  short* As = lds;
  short* Bs = lds + 64*128;
  const int t = threadIdx.x;
  const int m0 = blockIdx.x * 64;

  for (int c = t; c < 1024; c += 256){
    int row = c >> 4, k0 = (c & 15) << 3;
    u16x8 v = *(const u16x8*)&a[(m0+row)*128 + k0];
    int byte = (row<<8) + (k0<<1);
    *(u16x8*)((char*)As + (byte ^ ((row&7)<<4))) = v;
  }
  for (int c = t; c < 2048; c += 256){
    int n = c >> 4, k0 = (c & 15) << 3;
    u16x8 v = *(const u16x8*)&wpT[n*128 + k0];
    int byte = (n<<8) + (k0<<1);
    *(u16x8*)((char*)Bs + (byte ^ ((n&7)<<4))) = v;
  }
  __syncthreads();

  const int w = t >> 6, l = t & 63;
  const int wm = (w >> 1) * 32, wn = (w & 1) * 64;
  const int lr = l & 15, lk = (l >> 4) << 3;
  f32x4 acc[2][4] = {};
#pragma unroll
  for (int k0 = 0; k0 < 128; k0 += 32){
    const int koff = k0 + lk;
    short8 afr[2], bf[4];
#pragma unroll
    for (int fm = 0; fm < 2; ++fm){
      int row = wm + fm*16 + lr;
      int byte = (row<<8) + (koff<<1);
      afr[fm] = *(short8*)((char*)As + (byte ^ ((row&7)<<4)));
    }
#pragma unroll
    for (int fn = 0; fn < 4; ++fn){
      int rn = wn + fn*16 + lr;
      int byte = (rn<<8) + (koff<<1);
      bf[fn] = *(short8*)((char*)Bs + (byte ^ ((rn&7)<<4)));
    }
#pragma unroll
    for (int fm = 0; fm < 2; ++fm)
#pragma unroll
      for (int fn = 0; fn < 4; ++fn)
        acc[fm][fn] = __builtin_amdgcn_mfma_f32_16x16x32_bf16(afr[fm], bf[fn], acc[fm][fn], 0, 0, 0);
  }
  __syncthreads();

  float* C = (float*)lds;   // [64][132] fp32 = 33.8KB <= 48KB
#pragma unroll
  for (int fm = 0; fm < 2; ++fm)
#pragma unroll
    for (int fn = 0; fn < 4; ++fn){
      int col = wn + fn*16 + lr;
      float bv = bias[col];
#pragma unroll
      for (int r = 0; r < 4; ++r){
        int row = wm + fm*16 + ((l>>4)<<2) + r;
        C[row*132 + col] = acc[fm][fn][r] + bv;
      }
    }
  __syncthreads();
  for (int c = t; c < 2048; c += 256){
    int row = c >> 5, k0 = (c & 31) << 2;
    *(f4*)&out[(m0+row)*128 + k0] = *(const f4*)&C[row*132 + k0];
  }
}

extern "C" void kernel_launch(void* const* d_in, const int* in_sizes, int n_in,
                              void* d_out, int out_size, void* d_ws, size_t ws_size,
                              hipStream_t stream) {
  const float* x      = (const float*)d_in[0];
  const float* w_qkv  = (const float*)d_in[1];
  const float* b_qkv  = (const float*)d_in[2];
  const float* rpb    = (const float*)d_in[3];
  const float* w_proj = (const float*)d_in[4];
  const float* b_proj = (const float*)d_in[5];
  float* out = (float*)d_out;

  unsigned short* qo  = (unsigned short*)d_ws;
  unsigned short* ko  = qo + 16384*128;
  unsigned short* vo  = ko + 16384*128;
  unsigned short* ao  = vo + 16384*128;
  unsigned short* wT  = ao + 16384*128;
  unsigned short* wpT = wT + 384*128;

  k_prep<<<16, 256, 0, stream>>>(w_qkv, w_proj, wT, wpT);
  k_qkv_mfma<<<dim3(256, 3), 256, 0, stream>>>(x, wT, b_qkv, qo, ko, vo);
  k_attn<<<dim3(8, 8, 4), 256, 0, stream>>>(qo, ko, vo, rpb, ao);
  k_proj_mfma<<<256, 256, 0, stream>>>(ao, wpT, b_proj, out);
}

// Round 3
// 52.223 us; speedup vs baseline: 1.3593x; 1.0179x over previous
//
#include <hip/hip_runtime.h>
#include <hip/hip_bf16.h>

typedef float f4 __attribute__((ext_vector_type(4)));
typedef float f32x4 __attribute__((ext_vector_type(4)));
typedef unsigned short u16x8 __attribute__((ext_vector_type(8)));
typedef short short8 __attribute__((ext_vector_type(8)));

#define QSCALE 0.17677669529663689f  // 32^-0.5

__device__ inline float b2f(unsigned short u){
  union{unsigned int i; float f;} z; z.i = ((unsigned int)u)<<16; return z.f;
}
__device__ inline unsigned short f2b(float f){
  union{float f; unsigned int i;} z; z.f=f;
  unsigned int i = z.i;
  return (unsigned short)((i + 0x7FFFu + ((i>>16)&1u)) >> 16);
}

// ---------------- Kernel 0: transpose+convert weights ----------------
__global__ __launch_bounds__(256) void k_prep(const float* __restrict__ wq,
    const float* __restrict__ wp, unsigned short* __restrict__ wT,
    unsigned short* __restrict__ wpT)
{
  __shared__ float T[32][129];
  const int b = blockIdx.x, t = threadIdx.x;
  const float* src; unsigned short* dst; int N, n0;
  if (b < 12){ src = wq; dst = wT;  N = 384; n0 = b*32; }
  else       { src = wp; dst = wpT; N = 128; n0 = (b-12)*32; }
  for (int i = t; i < 4096; i += 256){
    int k = i >> 5, c = i & 31;
    T[c][k] = src[k*N + n0 + c];
  }
  __syncthreads();
  const int n = t >> 3, k0 = (t & 7) << 4;
#pragma unroll
  for (int e = 0; e < 2; ++e){
    u16x8 o;
#pragma unroll
    for (int j = 0; j < 8; ++j) o[j] = f2b(T[n][k0 + e*8 + j]);
    *(u16x8*)&dst[(n0+n)*128 + k0 + e*8] = o;
  }
}

// ---------------- Kernel 1: qkv = x @ w_qkv + b_qkv (MFMA bf16) ----------------
// grid (256, 3): m0 = bx*64, plane = by (0=q scaled,1=k,2=v). 4 waves.
// Output PLANAR: plane[(head*16384 + tok)*32 + d]
__global__ __launch_bounds__(256) void k_qkv_mfma(const float* __restrict__ x,
    const unsigned short* __restrict__ wT, const float* __restrict__ bias,
    unsigned short* __restrict__ qo, unsigned short* __restrict__ ko,
    unsigned short* __restrict__ vo)
{
  __shared__ short lds[64*128 + 128*128];   // As | Bs, 48KB
  short* As = lds;
  short* Bs = lds + 64*128;
  const int t = threadIdx.x;
  const int m0 = blockIdx.x * 64;
  const int ny = blockIdx.y;
  const int n0 = ny * 128;

  for (int c = t; c < 1024; c += 256){
    int row = c >> 4, k0 = (c & 15) << 3;
    const float* p = &x[(m0+row)*128 + k0];
    f4 lo = *(const f4*)p, hi = *(const f4*)(p+4);
    u16x8 v;
    v[0]=f2b(lo[0]); v[1]=f2b(lo[1]); v[2]=f2b(lo[2]); v[3]=f2b(lo[3]);
    v[4]=f2b(hi[0]); v[5]=f2b(hi[1]); v[6]=f2b(hi[2]); v[7]=f2b(hi[3]);
    int byte = (row<<8) + (k0<<1);
    *(u16x8*)((char*)As + (byte ^ ((row&7)<<4))) = v;
  }
  for (int c = t; c < 2048; c += 256){
    int n = c >> 4, k0 = (c & 15) << 3;
    u16x8 v = *(const u16x8*)&wT[(n0+n)*128 + k0];
    int byte = (n<<8) + (k0<<1);
    *(u16x8*)((char*)Bs + (byte ^ ((n&7)<<4))) = v;
  }
  __syncthreads();

  const int w = t >> 6, l = t & 63;
  const int wm = (w >> 1) * 32, wn = (w & 1) * 64;
  const int lr = l & 15, lk = (l >> 4) << 3;
  f32x4 acc[2][4] = {};
#pragma unroll
  for (int k0 = 0; k0 < 128; k0 += 32){
    const int koff = k0 + lk;
    short8 a[2], bf[4];
#pragma unroll
    for (int fm = 0; fm < 2; ++fm){
      int row = wm + fm*16 + lr;
      int byte = (row<<8) + (koff<<1);
      a[fm] = *(short8*)((char*)As + (byte ^ ((row&7)<<4)));
    }
#pragma unroll
    for (int fn = 0; fn < 4; ++fn){
      int rn = wn + fn*16 + lr;
      int byte = (rn<<8) + (koff<<1);
      bf[fn] = *(short8*)((char*)Bs + (byte ^ ((rn&7)<<4)));
    }
#pragma unroll
    for (int fm = 0; fm < 2; ++fm)
#pragma unroll
      for (int fn = 0; fn < 4; ++fn)
        acc[fm][fn] = __builtin_amdgcn_mfma_f32_16x16x32_bf16(a[fm], bf[fn], acc[fm][fn], 0, 0, 0);
  }
  __syncthreads();

  unsigned short* C = (unsigned short*)lds;   // [64][136]
  const float scale = (ny == 0) ? QSCALE : 1.0f;
#pragma unroll
  for (int fm = 0; fm < 2; ++fm)
#pragma unroll
    for (int fn = 0; fn < 4; ++fn){
      int col = wn + fn*16 + lr;
      float bv = bias[n0 + col];
#pragma unroll
      for (int r = 0; r < 4; ++r){
        int row = wm + fm*16 + ((l>>4)<<2) + r;
        C[row*136 + col] = f2b((acc[fm][fn][r] + bv) * scale);
      }
    }
  __syncthreads();
  unsigned short* dst = ny==0 ? qo : (ny==1 ? ko : vo);
  for (int c = t; c < 1024; c += 256){
    int row = c >> 4, k0 = (c & 15) << 3;
    int head = k0 >> 5, d0 = k0 & 31;
    *(u16x8*)&dst[(head*16384 + m0 + row)*32 + d0] = *(u16x8*)&C[row*136 + k0];
  }
}

// ---------------- Kernel 2: neighborhood attention ----------------
// grid (8, 8, 16): z = b*4 + h. One head per block. block 256 (4 waves).
// thread t: token lt = t>>2 (8x8 tile), neighbor-quarter p = t&3.
// LDS: 196 tokens x 32 dims bf16 (stride 40) for k and v, + rpb slice.
__global__ __launch_bounds__(256) void k_attn(
    const unsigned short* __restrict__ qg,
    const unsigned short* __restrict__ kg,
    const unsigned short* __restrict__ vg,
    const float* __restrict__ rpb,
    unsigned short* __restrict__ ao)
{
  __shared__ unsigned short ks[196*40];
  __shared__ unsigned short vs[196*40];
  __shared__ float rs[169];
  const int t = threadIdx.x;
  const int b = blockIdx.z >> 2, h = blockIdx.z & 3;
  const int th0 = blockIdx.y * 8, tw0 = blockIdx.x * 8;
  const int bi0 = min(max(th0-3,0),50);
  const int bj0 = min(max(tw0-3,0),50);
  const unsigned short* kb = kg + (h*16384 + b*4096)*32;
  const unsigned short* vb = vg + (h*16384 + b*4096)*32;

  for (int c = t; c < 784; c += 256){
    int tok = c >> 2, ch = c & 3;
    int trow = tok/14, tcol = tok - trow*14;
    int g = ((bi0+trow)*64 + (bj0+tcol))*32 + ch*8;
    int lo = tok*40 + ch*8;
    *(u16x8*)&ks[lo] = *(const u16x8*)&kb[g];
    *(u16x8*)&vs[lo] = *(const u16x8*)&vb[g];
  }
  for (int c = t; c < 169; c += 256) rs[c] = rpb[h*169 + c];
  __syncthreads();

  const int lt = t >> 2, p = t & 3;
  const int ti = th0 + (lt >> 3), tj = tw0 + (lt & 7);
  const int si = min(max(ti-3,0),57), sj = min(max(tj-3,0),57);
  const int li = si - bi0, lj = sj - bj0;
  const int ri = si - ti + 6, rj = sj - tj + 6;

  float q[32];
  {
    int qb = (h*16384 + b*4096 + ti*64 + tj)*32;
#pragma unroll
    for (int j=0;j<4;++j){
      u16x8 u = *(const u16x8*)&qg[qb + j*8];
#pragma unroll
      for (int e=0;e<8;++e) q[j*8+e] = b2f(u[e]);
    }
  }

  // phase 1: scores for neighbors n = p, p+4, ..., into regs
  float s[13]; int toks[13];
  float mx = -1e30f;
#pragma unroll
  for (int it = 0; it < 13; ++it){
    int n = p + (it << 2);
    bool ok = (n < 49);
    int nn = ok ? n : 48;
    int pi = nn / 7, pj = nn - pi*7;
    int tok = (li+pi)*14 + (lj+pj);
    toks[it] = tok;
    float acc = rs[(ri+pi)*13 + (rj+pj)];
#pragma unroll
    for (int j=0;j<4;++j){
      u16x8 kk = *(const u16x8*)&ks[tok*40 + j*8];
#pragma unroll
      for (int e=0;e<8;++e) acc += q[j*8+e]*b2f(kk[e]);
    }
    s[it] = ok ? acc : -1e30f;
    mx = fmaxf(mx, s[it]);
  }
  mx = fmaxf(mx, __shfl_xor(mx, 1));
  mx = fmaxf(mx, __shfl_xor(mx, 2));

  // phase 2: exp + PV accumulate
  float l = 0.f, o[32];
#pragma unroll
  for (int d=0; d<32; ++d) o[d] = 0.f;
#pragma unroll
  for (int it = 0; it < 13; ++it){
    float e = __expf(s[it] - mx);
    l += e;
    int tok = toks[it];
#pragma unroll
    for (int j=0;j<4;++j){
      u16x8 vv = *(const u16x8*)&vs[tok*40 + j*8];
#pragma unroll
      for (int e2=0;e2<8;++e2) o[j*8+e2] += e*b2f(vv[e2]);
    }
  }
  // merge the 4 neighbor-quarters (lanes differing in bits 0-1)
  l += __shfl_xor(l, 1);
  l += __shfl_xor(l, 2);
#pragma unroll
  for (int d=0; d<32; ++d) o[d] += __shfl_xor(o[d], 1);
#pragma unroll
  for (int d=0; d<32; ++d) o[d] += __shfl_xor(o[d], 2);

  float inv = 1.f / l;
  int ob = (b*4096 + ti*64 + tj)*128 + h*32 + p*8;
  u16x8 w8;
#pragma unroll
  for (int e=0;e<8;++e) w8[e] = f2b(o[p*8+e]*inv);
  *(u16x8*)&ao[ob] = w8;
}

// ---------------- Kernel 3: out = ao @ w_proj + b_proj (MFMA bf16, fp32 out) ---
__global__ __launch_bounds__(256) void k_proj_mfma(
    const unsigned short* __restrict__ a,
    const unsigned short* __restrict__ wpT, const float* __restrict__ bias,
    float* __restrict__ out)
{
  __shared__ short lds[64*128 + 128*128];
  short* As = lds;
  short* Bs = lds + 64*128;
  const int t = threadIdx.x;
  const int m0 = blockIdx.x * 64;

  for (int c = t; c < 1024; c += 256){
    int row = c >> 4, k0 = (c & 15) << 3;
    u16x8 v = *(const u16x8*)&a[(m0+row)*128 + k0];
    int byte = (row<<8) + (k0<<1);
    *(u16x8*)((char*)As + (byte ^ ((row&7)<<4))) = v;
  }
  for (int c = t; c < 2048; c += 256){
    int n = c >> 4, k0 = (c & 15) << 3;
    u16x8 v = *(const u16x8*)&wpT[n*128 + k0];
    int byte = (n<<8) + (k0<<1);
    *(u16x8*)((char*)Bs + (byte ^ ((n&7)<<4))) = v;
  }
  __syncthreads();

  const int w = t >> 6, l = t & 63;
  const int wm = (w >> 1) * 32, wn = (w & 1) * 64;
  const int lr = l & 15, lk = (l >> 4) << 3;
  f32x4 acc[2][4] = {};
#pragma unroll
  for (int k0 = 0; k0 < 128; k0 += 32){
    const int koff = k0 + lk;
    short8 afr[2], bf[4];
#pragma unroll
    for (int fm = 0; fm < 2; ++fm){
      int row = wm + fm*16 + lr;
      int byte = (row<<8) + (koff<<1);
      afr[fm] = *(short8*)((char*)As + (byte ^ ((row&7)<<4)));
    }
#pragma unroll
    for (int fn = 0; fn < 4; ++fn){
      int rn = wn + fn*16 + lr;
      int byte = (rn<<8) + (koff<<1);
      bf[fn] = *(short8*)((char*)Bs + (byte ^ ((rn&7)<<4)));
    }
#pragma unroll
    for (int fm = 0; fm < 2; ++fm)
#pragma unroll
      for (int fn = 0; fn < 4; ++fn)
        acc[fm][fn] = __builtin_amdgcn_mfma_f32_16x16x32_bf16(afr[fm], bf[fn], acc[fm][fn], 0, 0, 0);
  }
  __syncthreads();

  float* C = (float*)lds;   // [64][132]
#pragma unroll
  for (int fm = 0; fm < 2; ++fm)
#pragma unroll
    for (int fn = 0; fn < 4; ++fn){
      int col = wn + fn*16 + lr;
      float bv = bias[col];
#pragma unroll
      for (int r = 0; r < 4; ++r){
        int row = wm + fm*16 + ((l>>4)<<2) + r;
        C[row*132 + col] = acc[fm][fn][r] + bv;
      }
    }
  __syncthreads();
  for (int c = t; c < 2048; c += 256){
    int row = c >> 5, k0 = (c & 31) << 2;
    *(f4*)&out[(m0+row)*128 + k0] = *(const f4*)&C[row*132 + k0];
  }
}

extern "C" void kernel_launch(void* const* d_in, const int* in_sizes, int n_in,
                              void* d_out, int out_size, void* d_ws, size_t ws_size,
                              hipStream_t stream) {
  const float* x      = (const float*)d_in[0];
  const float* w_qkv  = (const float*)d_in[1];
  const float* b_qkv  = (const float*)d_in[2];
  const float* rpb    = (const float*)d_in[3];
  const float* w_proj = (const float*)d_in[4];
  const float* b_proj = (const float*)d_in[5];
  float* out = (float*)d_out;

  unsigned short* qo  = (unsigned short*)d_ws;
  unsigned short* ko  = qo + 16384*128;
  unsigned short* vo  = ko + 16384*128;
  unsigned short* ao  = vo + 16384*128;
  unsigned short* wT  = ao + 16384*128;
  unsigned short* wpT = wT + 384*128;

  k_prep<<<16, 256, 0, stream>>>(w_qkv, w_proj, wT, wpT);
  k_qkv_mfma<<<dim3(256, 3), 256, 0, stream>>>(x, wT, b_qkv, qo, ko, vo);
  k_attn<<<dim3(8, 8, 16), 256, 0, stream>>>(qo, ko, vo, rpb, ao);
  k_proj_mfma<<<256, 256, 0, stream>>>(ao, wpT, b_proj, out);
}

// Round 4
// 45.424 us; speedup vs baseline: 1.5627x; 1.1497x over previous
//
#include <hip/hip_runtime.h>
#include <hip/hip_bf16.h>

typedef float f4 __attribute__((ext_vector_type(4)));
typedef float f32x4 __attribute__((ext_vector_type(4)));
typedef unsigned short u16x8 __attribute__((ext_vector_type(8)));
typedef short short8 __attribute__((ext_vector_type(8)));
typedef unsigned int uint2v __attribute__((ext_vector_type(2)));

#define QSCALE 0.17677669529663689f  // 32^-0.5

__device__ inline float b2f(unsigned short u){
  union{unsigned int i; float f;} z; z.i = ((unsigned int)u)<<16; return z.f;
}
__device__ inline unsigned short f2b(float f){
  union{float f; unsigned int i;} z; z.f=f;
  unsigned int i = z.i;
  return (unsigned short)((i + 0x7FFFu + ((i>>16)&1u)) >> 16);
}

// ---------------- Kernel 1: qkv = x @ w_qkv + b_qkv (MFMA bf16) ----------------
// grid (256, 3): m0 = bx*64, plane ny (0=q scaled,1=k,2=v). 4 waves.
// B staged straight from fp32 w via in-register 4x4 transpose.
// Output PLANAR: plane[(head*16384 + tok)*32 + d]
__global__ __launch_bounds__(256) void k_qkv_mfma(const float* __restrict__ x,
    const float* __restrict__ w, const float* __restrict__ bias,
    unsigned short* __restrict__ qo, unsigned short* __restrict__ ko,
    unsigned short* __restrict__ vo)
{
  __shared__ short lds[64*128 + 128*128];   // As | Bs, 48KB
  short* As = lds;             // [64][128] bf16 row stride 256B, XOR swizzled
  short* Bs = lds + 64*128;    // [n][k] bf16, swizzled
  const int t = threadIdx.x;
  const int m0 = blockIdx.x * 64;
  const int ny = blockIdx.y;
  const int n0 = ny * 128;

  // stage A: x fp32 -> bf16, swizzled
  for (int c = t; c < 1024; c += 256){
    int row = c >> 4, k0 = (c & 15) << 3;
    const float* p = &x[(m0+row)*128 + k0];
    f4 lo = *(const f4*)p, hi = *(const f4*)(p+4);
    u16x8 v;
    v[0]=f2b(lo[0]); v[1]=f2b(lo[1]); v[2]=f2b(lo[2]); v[3]=f2b(lo[3]);
    v[4]=f2b(hi[0]); v[5]=f2b(hi[1]); v[6]=f2b(hi[2]); v[7]=f2b(hi[3]);
    int byte = (row<<8) + (k0<<1);
    *(u16x8*)((char*)As + (byte ^ ((row&7)<<4))) = v;
  }
  // stage B: w[k][n0+n] fp32 -> Bs[n][k] bf16, 4x4 reg transpose
  for (int c = t; c < 1024; c += 256){
    int kb = c >> 5, nb = c & 31;           // 4-row, 4-col sub-block
    const float* p = &w[(kb*4)*384 + n0 + nb*4];
    f4 r0 = *(const f4*)p;
    f4 r1 = *(const f4*)(p + 384);
    f4 r2 = *(const f4*)(p + 768);
    f4 r3 = *(const f4*)(p + 1152);
#pragma unroll
    for (int j = 0; j < 4; ++j){
      int n = nb*4 + j;
      uint2v val;
      val[0] = (unsigned int)f2b(r0[j]) | ((unsigned int)f2b(r1[j])<<16);
      val[1] = (unsigned int)f2b(r2[j]) | ((unsigned int)f2b(r3[j])<<16);
      int byte = (n<<8) + (kb<<3);
      *(uint2v*)((char*)Bs + (byte ^ ((n&7)<<4))) = val;
    }
  }
  __syncthreads();

  const int wv = t >> 6, l = t & 63;
  const int wm = (wv >> 1) * 32, wn = (wv & 1) * 64;
  const int lr = l & 15, lk = (l >> 4) << 3;
  f32x4 acc[2][4] = {};
#pragma unroll
  for (int k0 = 0; k0 < 128; k0 += 32){
    const int koff = k0 + lk;
    short8 a[2], bf[4];
#pragma unroll
    for (int fm = 0; fm < 2; ++fm){
      int row = wm + fm*16 + lr;
      int byte = (row<<8) + (koff<<1);
      a[fm] = *(short8*)((char*)As + (byte ^ ((row&7)<<4)));
    }
#pragma unroll
    for (int fn = 0; fn < 4; ++fn){
      int rn = wn + fn*16 + lr;
      int byte = (rn<<8) + (koff<<1);
      bf[fn] = *(short8*)((char*)Bs + (byte ^ ((rn&7)<<4)));
    }
#pragma unroll
    for (int fm = 0; fm < 2; ++fm)
#pragma unroll
      for (int fn = 0; fn < 4; ++fn)
        acc[fm][fn] = __builtin_amdgcn_mfma_f32_16x16x32_bf16(a[fm], bf[fn], acc[fm][fn], 0, 0, 0);
  }
  __syncthreads();

  unsigned short* C = (unsigned short*)lds;   // [64][136]
  const float scale = (ny == 0) ? QSCALE : 1.0f;
#pragma unroll
  for (int fm = 0; fm < 2; ++fm)
#pragma unroll
    for (int fn = 0; fn < 4; ++fn){
      int col = wn + fn*16 + lr;
      float bv = bias[n0 + col];
#pragma unroll
      for (int r = 0; r < 4; ++r){
        int row = wm + fm*16 + ((l>>4)<<2) + r;
        C[row*136 + col] = f2b((acc[fm][fn][r] + bv) * scale);
      }
    }
  __syncthreads();
  unsigned short* dst = ny==0 ? qo : (ny==1 ? ko : vo);
  for (int c = t; c < 1024; c += 256){
    int row = c >> 4, k0 = (c & 15) << 3;
    int head = k0 >> 5, d0 = k0 & 31;
    *(u16x8*)&dst[(head*16384 + m0 + row)*32 + d0] = *(u16x8*)&C[row*136 + k0];
  }
}

// ---------------- Kernel 2: neighborhood attention ----------------
// grid (8, 8, 16): z = b*4 + h. One head per block. block 256 (4 waves).
__global__ __launch_bounds__(256) void k_attn(
    const unsigned short* __restrict__ qg,
    const unsigned short* __restrict__ kg,
    const unsigned short* __restrict__ vg,
    const float* __restrict__ rpb,
    unsigned short* __restrict__ ao)
{
  __shared__ unsigned short ks[196*40];
  __shared__ unsigned short vs[196*40];
  __shared__ float rs[169];
  const int t = threadIdx.x;
  const int b = blockIdx.z >> 2, h = blockIdx.z & 3;
  const int th0 = blockIdx.y * 8, tw0 = blockIdx.x * 8;
  const int bi0 = min(max(th0-3,0),50);
  const int bj0 = min(max(tw0-3,0),50);
  const unsigned short* kb = kg + (h*16384 + b*4096)*32;
  const unsigned short* vb = vg + (h*16384 + b*4096)*32;

  // q load issued before staging so global latency hides under LDS writes
  const int lt = t >> 2, p = t & 3;
  const int ti = th0 + (lt >> 3), tj = tw0 + (lt & 7);
  float q[32];
  {
    int qb = (h*16384 + b*4096 + ti*64 + tj)*32;
#pragma unroll
    for (int j=0;j<4;++j){
      u16x8 u = *(const u16x8*)&qg[qb + j*8];
#pragma unroll
      for (int e=0;e<8;++e) q[j*8+e] = b2f(u[e]);
    }
  }

  for (int c = t; c < 784; c += 256){
    int tok = c >> 2, ch = c & 3;
    int trow = tok/14, tcol = tok - trow*14;
    int g = ((bi0+trow)*64 + (bj0+tcol))*32 + ch*8;
    int lo = tok*40 + ch*8;
    *(u16x8*)&ks[lo] = *(const u16x8*)&kb[g];
    *(u16x8*)&vs[lo] = *(const u16x8*)&vb[g];
  }
  for (int c = t; c < 169; c += 256) rs[c] = rpb[h*169 + c];
  __syncthreads();

  const int si = min(max(ti-3,0),57), sj = min(max(tj-3,0),57);
  const int li = si - bi0, lj = sj - bj0;
  const int ri = si - ti + 6, rj = sj - tj + 6;

  // phase 1: scores for neighbors n = p, p+4, ...
  float s[13]; int toks[13];
  float mx = -1e30f;
#pragma unroll
  for (int it = 0; it < 13; ++it){
    int n = p + (it << 2);
    bool ok = (n < 49);
    int nn = ok ? n : 48;
    int pi = nn / 7, pj = nn - pi*7;
    int tok = (li+pi)*14 + (lj+pj);
    toks[it] = tok;
    float acc = rs[(ri+pi)*13 + (rj+pj)];
#pragma unroll
    for (int j=0;j<4;++j){
      u16x8 kk = *(const u16x8*)&ks[tok*40 + j*8];
#pragma unroll
      for (int e=0;e<8;++e) acc += q[j*8+e]*b2f(kk[e]);
    }
    s[it] = ok ? acc : -1e30f;
    mx = fmaxf(mx, s[it]);
  }
  mx = fmaxf(mx, __shfl_xor(mx, 1));
  mx = fmaxf(mx, __shfl_xor(mx, 2));

  // phase 2: exp + PV accumulate
  float l = 0.f, o[32];
#pragma unroll
  for (int d=0; d<32; ++d) o[d] = 0.f;
#pragma unroll
  for (int it = 0; it < 13; ++it){
    float e = __expf(s[it] - mx);
    l += e;
    int tok = toks[it];
#pragma unroll
    for (int j=0;j<4;++j){
      u16x8 vv = *(const u16x8*)&vs[tok*40 + j*8];
#pragma unroll
      for (int e2=0;e2<8;++e2) o[j*8+e2] += e*b2f(vv[e2]);
    }
  }
  l += __shfl_xor(l, 1);
  l += __shfl_xor(l, 2);
#pragma unroll
  for (int d=0; d<32; ++d) o[d] += __shfl_xor(o[d], 1);
#pragma unroll
  for (int d=0; d<32; ++d) o[d] += __shfl_xor(o[d], 2);

  float inv = 1.f / l;
  int ob = (b*4096 + ti*64 + tj)*128 + h*32 + p*8;
  u16x8 w8;
#pragma unroll
  for (int e=0;e<8;++e) w8[e] = f2b(o[p*8+e]*inv);
  *(u16x8*)&ao[ob] = w8;
}

// ---------------- Kernel 3: out = ao @ w_proj + b_proj (MFMA bf16, fp32 out) ---
// grid (256, 2): m0 = bx*64, n0 = by*64. block 256 (4 waves), wave tile 32x32.
__global__ __launch_bounds__(256) void k_proj_mfma(
    const unsigned short* __restrict__ a,
    const float* __restrict__ w, const float* __restrict__ bias,
    float* __restrict__ out)
{
  __shared__ short lds[64*128 + 64*128];   // As | Bs, 32KB
  short* As = lds;
  short* Bs = lds + 64*128;
  const int t = threadIdx.x;
  const int m0 = blockIdx.x * 64;
  const int n0 = blockIdx.y * 64;

  for (int c = t; c < 1024; c += 256){
    int row = c >> 4, k0 = (c & 15) << 3;
    u16x8 v = *(const u16x8*)&a[(m0+row)*128 + k0];
    int byte = (row<<8) + (k0<<1);
    *(u16x8*)((char*)As + (byte ^ ((row&7)<<4))) = v;
  }
  // stage B: w_proj[k][n0+n] fp32 -> Bs[n][k] bf16 via 4x4 reg transpose
  for (int c = t; c < 512; c += 256){
    int kb = c >> 4, nb = c & 15;
    const float* p = &w[(kb*4)*128 + n0 + nb*4];
    f4 r0 = *(const f4*)p;
    f4 r1 = *(const f4*)(p + 128);
    f4 r2 = *(const f4*)(p + 256);
    f4 r3 = *(const f4*)(p + 384);
#pragma unroll
    for (int j = 0; j < 4; ++j){
      int n = nb*4 + j;
      uint2v val;
      val[0] = (unsigned int)f2b(r0[j]) | ((unsigned int)f2b(r1[j])<<16);
      val[1] = (unsigned int)f2b(r2[j]) | ((unsigned int)f2b(r3[j])<<16);
      int byte = (n<<8) + (kb<<3);
      *(uint2v*)((char*)Bs + (byte ^ ((n&7)<<4))) = val;
    }
  }
  __syncthreads();

  const int wv = t >> 6, l = t & 63;
  const int wm = (wv >> 1) * 32, wn = (wv & 1) * 32;
  const int lr = l & 15, lk = (l >> 4) << 3;
  f32x4 acc[2][2] = {};
#pragma unroll
  for (int k0 = 0; k0 < 128; k0 += 32){
    const int koff = k0 + lk;
    short8 afr[2], bf[2];
#pragma unroll
    for (int fm = 0; fm < 2; ++fm){
      int row = wm + fm*16 + lr;
      int byte = (row<<8) + (koff<<1);
      afr[fm] = *(short8*)((char*)As + (byte ^ ((row&7)<<4)));
    }
#pragma unroll
    for (int fn = 0; fn < 2; ++fn){
      int rn = wn + fn*16 + lr;
      int byte = (rn<<8) + (koff<<1);
      bf[fn] = *(short8*)((char*)Bs + (byte ^ ((rn&7)<<4)));
    }
#pragma unroll
    for (int fm = 0; fm < 2; ++fm)
#pragma unroll
      for (int fn = 0; fn < 2; ++fn)
        acc[fm][fn] = __builtin_amdgcn_mfma_f32_16x16x32_bf16(afr[fm], bf[fn], acc[fm][fn], 0, 0, 0);
  }
  __syncthreads();

  float* C = (float*)lds;   // [64][68] fp32 = 17.4KB
#pragma unroll
  for (int fm = 0; fm < 2; ++fm)
#pragma unroll
    for (int fn = 0; fn < 2; ++fn){
      int col = wn + fn*16 + lr;
      float bv = bias[n0 + col];
#pragma unroll
      for (int r = 0; r < 4; ++r){
        int row = wm + fm*16 + ((l>>4)<<2) + r;
        C[row*68 + col] = acc[fm][fn][r] + bv;
      }
    }
  __syncthreads();
  for (int c = t; c < 1024; c += 256){
    int row = c >> 4, colc = (c & 15) << 2;
    *(f4*)&out[(m0+row)*128 + n0 + colc] = *(const f4*)&C[row*68 + colc];
  }
}

extern "C" void kernel_launch(void* const* d_in, const int* in_sizes, int n_in,
                              void* d_out, int out_size, void* d_ws, size_t ws_size,
                              hipStream_t stream) {
  const float* x      = (const float*)d_in[0];
  const float* w_qkv  = (const float*)d_in[1];
  const float* b_qkv  = (const float*)d_in[2];
  const float* rpb    = (const float*)d_in[3];
  const float* w_proj = (const float*)d_in[4];
  const float* b_proj = (const float*)d_in[5];
  float* out = (float*)d_out;

  unsigned short* qo  = (unsigned short*)d_ws;
  unsigned short* ko  = qo + 16384*128;
  unsigned short* vo  = ko + 16384*128;
  unsigned short* ao  = vo + 16384*128;

  k_qkv_mfma<<<dim3(256, 3), 256, 0, stream>>>(x, w_qkv, b_qkv, qo, ko, vo);
  k_attn<<<dim3(8, 8, 16), 256, 0, stream>>>(qo, ko, vo, rpb, ao);
  k_proj_mfma<<<dim3(256, 2), 256, 0, stream>>>(ao, w_proj, b_proj, out);
}